// Round 1
// baseline (380.090 us; speedup 1.0000x reference)
//
#include <hip/hip_runtime.h>

typedef unsigned short u16;
typedef __attribute__((ext_vector_type(8))) short bf16x8;   // 8 bf16 = 4 VGPRs (MFMA A/B frag)
typedef __attribute__((ext_vector_type(4))) float f32x4;    // MFMA C/D frag

__device__ __forceinline__ u16 f2bf(float f) {
  unsigned u = __float_as_uint(f);
  u = u + 0x7fffu + ((u >> 16) & 1u);   // RNE
  return (u16)(u >> 16);
}
__device__ __forceinline__ float bf2f(short s) {
  return __uint_as_float(((unsigned)(u16)s) << 16);
}

// ---------------- prep: f32 -> bf16 elementwise ----------------
__global__ void conv_f32_bf16(const float* __restrict__ in, u16* __restrict__ out, int n4) {
  int i = blockIdx.x * blockDim.x + threadIdx.x;
  int stride = gridDim.x * blockDim.x;
  for (; i < n4; i += stride) {
    float4 v = ((const float4*)in)[i];
    ushort4 o = make_ushort4(f2bf(v.x), f2bf(v.y), f2bf(v.z), f2bf(v.w));
    ((ushort4*)out)[i] = o;
  }
}

// ---------------- prep: W[k][n] f32 -> Wt[n][k] bf16 ----------------
__global__ void wtrans(const float* __restrict__ W, u16* __restrict__ Wt) {
  __shared__ float T[32][33];
  int k0 = blockIdx.y * 32, n0 = blockIdx.x * 32;
  int tx = threadIdx.x, ty = threadIdx.y;       // (32,8)
  #pragma unroll
  for (int j = 0; j < 4; ++j) T[ty + 8*j][tx] = W[(size_t)(k0 + ty + 8*j) * 1024 + n0 + tx];
  __syncthreads();
  #pragma unroll
  for (int j = 0; j < 4; ++j) Wt[(size_t)(n0 + ty + 8*j) * 1024 + k0 + tx] = f2bf(T[tx][ty + 8*j]);
}

// ---------------- QKV projection GEMM ----------------
// C[s][n] = sum_k X[s][k] * Wt[n][k] + bias[n]; out stored [B,H,S,64] bf16.
__global__ __launch_bounds__(256) void qkv_gemm(const u16* __restrict__ X, const u16* __restrict__ Wt,
                                                const float* __restrict__ bias, u16* __restrict__ outp) {
  __shared__ __align__(16) u16 As[128 * 32];
  __shared__ __align__(16) u16 Bs[128 * 32];
  int tid = threadIdx.x;
  int m0 = blockIdx.y * 128, n0 = blockIdx.x * 128;
  int w = tid >> 6, l = tid & 63;
  int wm = w >> 1, wn = w & 1;
  f32x4 acc[4][4] = {};
  for (int kt = 0; kt < 32; ++kt) {
    #pragma unroll
    for (int c = 0; c < 2; ++c) {
      int i = c * 256 + tid;              // 0..511 int4 chunks
      int row = i >> 2, kc = i & 3;
      ((int4*)As)[i] = ((const int4*)X)[(size_t)(m0 + row) * 128 + kt * 4 + kc];
      ((int4*)Bs)[i] = ((const int4*)Wt)[(size_t)(n0 + row) * 128 + kt * 4 + kc];
    }
    __syncthreads();
    bf16x8 a[4], bb[4];
    #pragma unroll
    for (int mc = 0; mc < 4; ++mc) a[mc]  = *(const bf16x8*)&As[(wm*64 + mc*16 + (l & 15)) * 32 + (l >> 4) * 8];
    #pragma unroll
    for (int nc = 0; nc < 4; ++nc) bb[nc] = *(const bf16x8*)&Bs[(wn*64 + nc*16 + (l & 15)) * 32 + (l >> 4) * 8];
    #pragma unroll
    for (int mc = 0; mc < 4; ++mc)
      #pragma unroll
      for (int nc = 0; nc < 4; ++nc)
        acc[mc][nc] = __builtin_amdgcn_mfma_f32_16x16x32_bf16(a[mc], bb[nc], acc[mc][nc], 0, 0, 0);
    __syncthreads();
  }
  #pragma unroll
  for (int nc = 0; nc < 4; ++nc) {
    int n = n0 + wn * 64 + nc * 16 + (l & 15);
    float bv = bias[n];
    int h = n >> 6, d = n & 63;
    #pragma unroll
    for (int mc = 0; mc < 4; ++mc) {
      int srow_base = m0 + wm * 64 + mc * 16 + (l >> 4) * 4;
      #pragma unroll
      for (int r = 0; r < 4; ++r) {
        int sm = srow_base + r;
        int b = sm >> 10, s = sm & 1023;
        outp[((size_t)((b * 16 + h) * 1024 + s)) * 64 + d] = f2bf(acc[mc][nc][r] + bv);
      }
    }
  }
}

// ---------------- V [B,H,S,64] -> Vt [B,H,64,S] ----------------
__global__ void vtrans(const u16* __restrict__ V, u16* __restrict__ Vt) {
  __shared__ u16 T[64][65];
  int bh = blockIdx.y;
  int s0 = blockIdx.x * 64;
  int tx = threadIdx.x, ty = threadIdx.y;       // (64,4)
  #pragma unroll
  for (int j = 0; j < 16; ++j) T[ty + 4*j][tx] = V[((size_t)bh * 1024 + s0 + ty + 4*j) * 64 + tx];
  __syncthreads();
  #pragma unroll
  for (int j = 0; j < 16; ++j) Vt[((size_t)bh * 64 + ty + 4*j) * 1024 + s0 + tx] = T[tx][ty + 4*j];
}

// ---------------- fused double-softmax attention ----------------
// grid 4096 = 8 XCD x 16 bh x 32 qtiles; block 256 = 4 waves (2 qsub x 2 khalf)
__global__ __launch_bounds__(256, 2) void attn(const u16* __restrict__ Q, const u16* __restrict__ K,
                                               const u16* __restrict__ Vt, const float* __restrict__ mask,
                                               const int* __restrict__ clp, float* __restrict__ out) {
  __shared__ float maskL[1024];
  __shared__ __align__(16) u16 sc[32 * 1024];   // XOR-swizzled bf16 scores
  __shared__ float m1h[2][32];
  __shared__ float z1p[4][32];
  __shared__ float m1s[32];
  __shared__ float iZ1[32];
  __shared__ float z2h[2][32];
  __shared__ float redO[2][16][66];

  int bid = blockIdx.x;
  int xcd = bid & 7, idx = bid >> 3;
  int bh = xcd * 16 + (idx >> 5);   // same-XCD blocks share (b,h) -> K/V stay L2-resident
  int qt = idx & 31;
  int b = bh >> 4, h = bh & 15;
  int tid = threadIdx.x;
  int w = tid >> 6, l = tid & 63;
  int qsub = w >> 1, kh = w & 1;
  int qbase = qt * 32 + qsub * 16;

  for (int i = tid; i < 1024; i += 256) maskL[i] = mask[b * 1024 + i];

  const u16* Qp = Q + ((size_t)bh * 1024 + qbase + (l & 15)) * 64 + (l >> 4) * 8;
  bf16x8 qf0 = *(const bf16x8*)Qp;
  bf16x8 qf1 = *(const bf16x8*)(Qp + 32);
  __syncthreads();

  // ---- sweep A: QK^T -> swizzled LDS scores + running row max ----
  float rmax[4] = {-1e30f, -1e30f, -1e30f, -1e30f};
  const u16* Kb = K + (size_t)bh * 1024 * 64;
  for (int t = 0; t < 16; ++t) {
    int k0 = kh * 512 + t * 32;
    #pragma unroll
    for (int nc = 0; nc < 2; ++nc) {
      int key = k0 + nc * 16 + (l & 15);
      const u16* Kp = Kb + (size_t)key * 64 + (l >> 4) * 8;
      bf16x8 kf0 = *(const bf16x8*)Kp;
      bf16x8 kf1 = *(const bf16x8*)(Kp + 32);
      f32x4 s = {0.f, 0.f, 0.f, 0.f};
      s = __builtin_amdgcn_mfma_f32_16x16x32_bf16(qf0, kf0, s, 0, 0, 0);
      s = __builtin_amdgcn_mfma_f32_16x16x32_bf16(qf1, kf1, s, 0, 0, 0);
      float mk = maskL[key];
      #pragma unroll
      for (int r = 0; r < 4; ++r) {
        float sv = s[r] * 0.125f + mk;
        rmax[r] = fmaxf(rmax[r], sv);
        int q = qsub * 16 + (l >> 4) * 4 + r;
        sc[q * 1024 + (key ^ ((q & 7) << 3))] = f2bf(sv);
      }
    }
  }
  #pragma unroll
  for (int r = 0; r < 4; ++r) {
    float v = rmax[r];
    v = fmaxf(v, __shfl_xor(v, 1));
    v = fmaxf(v, __shfl_xor(v, 2));
    v = fmaxf(v, __shfl_xor(v, 4));
    v = fmaxf(v, __shfl_xor(v, 8));
    rmax[r] = v;
  }
  if ((l & 15) == 0) {
    #pragma unroll
    for (int r = 0; r < 4; ++r) m1h[kh][qsub * 16 + (l >> 4) * 4 + r] = rmax[r];
  }
  __syncthreads();

  // ---- B1: Z1 per q row ----
  {
    int q = tid & 31;
    int gg = (tid >> 5) & 7;
    float m1q = fmaxf(m1h[0][q], m1h[1][q]);
    float z = 0.f;
    for (int j = 0; j < 16; ++j) {
      int k = gg * 8 + j * 64;
      bf16x8 v = *(const bf16x8*)&sc[q * 1024 + (k ^ ((q & 7) << 3))];
      #pragma unroll
      for (int i = 0; i < 8; ++i) z += __expf(bf2f(v[i]) - m1q);
    }
    z += __shfl_xor(z, 32);
    if (l < 32) z1p[w][q] = z;
    __syncthreads();
    if (tid < 32) {
      float zt = z1p[0][tid] + z1p[1][tid] + z1p[2][tid] + z1p[3][tid];
      m1s[tid] = fmaxf(m1h[0][tid], m1h[1][tid]);
      iZ1[tid] = 1.0f / zt;
    }
    __syncthreads();
  }

  // ---- B2: second softmax (m2=0; softmax(1-p+mask)=softmax(mask-p)) + PV ----
  int cl = clp[0];
  int qA = qsub * 16 + (l & 15);
  float m1v = m1s[qA];
  float iz1 = iZ1[qA];
  f32x4 acc[4] = {};
  float z2 = 0.f;
  const u16* Vb = Vt + (size_t)bh * 64 * 1024;
  int g8 = (l >> 4) * 8;
  for (int t = 0; t < 16; ++t) {
    int k0 = kh * 512 + t * 32;
    int kk0 = k0 + g8;
    bf16x8 sv = *(const bf16x8*)&sc[qA * 1024 + (kk0 ^ ((qA & 7) << 3))];
    bf16x8 p2f;
    if (cl) {
      float4 mk0 = *(const float4*)&maskL[kk0];
      float4 mk1 = *(const float4*)&maskL[kk0 + 4];
      float mkv[8] = {mk0.x, mk0.y, mk0.z, mk0.w, mk1.x, mk1.y, mk1.z, mk1.w};
      #pragma unroll
      for (int i = 0; i < 8; ++i) {
        float s = bf2f(sv[i]);
        float p = __expf(s - m1v) * iz1;     // probs1 in [0,1]
        float p2 = __expf(mkv[i] - p);       // mask<=0 -> arg<=0, no overflow
        z2 += p2;
        p2f[i] = (short)f2bf(p2);
      }
    } else {
      #pragma unroll
      for (int i = 0; i < 8; ++i) {
        float s = bf2f(sv[i]);
        p2f[i] = (short)f2bf(__expf(s - m1v));   // unnormalized probs1; scale by iZ1 at end
      }
    }
    #pragma unroll
    for (int dc = 0; dc < 4; ++dc) {
      bf16x8 vf = *(const bf16x8*)(Vb + (size_t)(dc * 16 + (l & 15)) * 1024 + kk0);
      acc[dc] = __builtin_amdgcn_mfma_f32_16x16x32_bf16(p2f, vf, acc[dc], 0, 0, 0);
    }
  }
  z2 += __shfl_xor(z2, 16);
  z2 += __shfl_xor(z2, 32);
  if (l < 16) z2h[kh][qsub * 16 + l] = z2;
  __syncthreads();
  if (kh == 1) {
    #pragma unroll
    for (int dc = 0; dc < 4; ++dc)
      #pragma unroll
      for (int r = 0; r < 4; ++r)
        redO[qsub][(l >> 4) * 4 + r][dc * 16 + (l & 15)] = acc[dc][r];
  }
  __syncthreads();
  if (kh == 0) {
    #pragma unroll
    for (int r = 0; r < 4; ++r) {
      int qq = qsub * 16 + (l >> 4) * 4 + r;
      float scale = cl ? (1.0f / (z2h[0][qq] + z2h[1][qq])) : iZ1[qq];
      int qg = qt * 32 + qq;
      #pragma unroll
      for (int dc = 0; dc < 4; ++dc) {
        float o = acc[dc][r] + redO[qsub][(l >> 4) * 4 + r][dc * 16 + (l & 15)];
        out[((size_t)(b * 1024 + qg)) * 1024 + h * 64 + dc * 16 + (l & 15)] = o * scale;
      }
    }
  }
}

extern "C" void kernel_launch(void* const* d_in, const int* in_sizes, int n_in,
                              void* d_out, int out_size, void* d_ws, size_t ws_size,
                              hipStream_t stream) {
  const float* s1   = (const float*)d_in[0];
  const float* s2   = (const float*)d_in[1];
  const float* mask = (const float*)d_in[2];
  const float* Wq   = (const float*)d_in[3];
  const float* bq   = (const float*)d_in[4];
  const float* Wk   = (const float*)d_in[5];
  const float* bk   = (const float*)d_in[6];
  const float* Wv   = (const float*)d_in[7];
  const float* bv   = (const float*)d_in[8];
  const int*   cl   = (const int*)d_in[9];
  float* out = (float*)d_out;

  // ws layout (u16 elements): X1[8M] X2[8M] Wtq[1M] Wtk[1M] Wtv[1M] Q[8M] K[8M] V[8M] = 86 MB
  u16* ws  = (u16*)d_ws;
  const size_t M1 = 1024 * 1024;
  u16* X1  = ws;
  u16* X2  = ws + 8 * M1;
  u16* Wtq = ws + 16 * M1;
  u16* Wtk = Wtq + M1;
  u16* Wtv = Wtk + M1;
  u16* Qb  = Wtv + M1;
  u16* Kb  = Qb + 8 * M1;
  u16* Vb  = Kb + 8 * M1;
  u16* Vtb = X1;   // alias: X1 is dead after the Q projection

  conv_f32_bf16<<<2048, 256, 0, stream>>>(s1, X1, 2097152);
  conv_f32_bf16<<<2048, 256, 0, stream>>>(s2, X2, 2097152);
  dim3 wtb(32, 8);
  wtrans<<<dim3(32, 32), wtb, 0, stream>>>(Wq, Wtq);
  wtrans<<<dim3(32, 32), wtb, 0, stream>>>(Wk, Wtk);
  wtrans<<<dim3(32, 32), wtb, 0, stream>>>(Wv, Wtv);
  qkv_gemm<<<dim3(8, 64), 256, 0, stream>>>(X1, Wtq, bq, Qb);
  qkv_gemm<<<dim3(8, 64), 256, 0, stream>>>(X2, Wtk, bk, Kb);
  qkv_gemm<<<dim3(8, 64), 256, 0, stream>>>(X2, Wtv, bv, Vb);
  vtrans<<<dim3(16, 128), dim3(64, 4), 0, stream>>>(Vb, Vtb);
  attn<<<4096, 256, 0, stream>>>(Qb, Kb, Vtb, mask, cl, out);
}

// Round 2
// 354.483 us; speedup vs baseline: 1.0722x; 1.0722x over previous
//
#include <hip/hip_runtime.h>

typedef unsigned short u16;
typedef __attribute__((ext_vector_type(8))) short bf16x8;   // 8 bf16 = 4 VGPRs (MFMA A/B frag)
typedef __attribute__((ext_vector_type(4))) float f32x4;    // MFMA C/D frag

#define L2E 1.4426950408889634f

__device__ __forceinline__ u16 f2bf(float f) {
  unsigned u = __float_as_uint(f);
  u = u + 0x7fffu + ((u >> 16) & 1u);   // RNE
  return (u16)(u >> 16);
}
__device__ __forceinline__ float bf2f(short s) {
  return __uint_as_float(((unsigned)(u16)s) << 16);
}

// ---------------- prep: f32 -> bf16 elementwise ----------------
__global__ void conv_f32_bf16(const float* __restrict__ in, u16* __restrict__ out, int n4) {
  int i = blockIdx.x * blockDim.x + threadIdx.x;
  int stride = gridDim.x * blockDim.x;
  for (; i < n4; i += stride) {
    float4 v = ((const float4*)in)[i];
    ushort4 o = make_ushort4(f2bf(v.x), f2bf(v.y), f2bf(v.z), f2bf(v.w));
    ((ushort4*)out)[i] = o;
  }
}

// ---------------- prep: W[k][n] f32 -> Wt[n][k] bf16 ----------------
__global__ void wtrans(const float* __restrict__ W, u16* __restrict__ Wt) {
  __shared__ float T[32][33];
  int k0 = blockIdx.y * 32, n0 = blockIdx.x * 32;
  int tx = threadIdx.x, ty = threadIdx.y;       // (32,8)
  #pragma unroll
  for (int j = 0; j < 4; ++j) T[ty + 8*j][tx] = W[(size_t)(k0 + ty + 8*j) * 1024 + n0 + tx];
  __syncthreads();
  #pragma unroll
  for (int j = 0; j < 4; ++j) Wt[(size_t)(n0 + ty + 8*j) * 1024 + k0 + tx] = f2bf(T[tx][ty + 8*j]);
}

// ---------------- QKV projection GEMM (3 fused via blockIdx.z) ----------------
__global__ __launch_bounds__(256) void qkv_gemm3(const u16* __restrict__ X1, const u16* __restrict__ X2,
                                                 const u16* __restrict__ Wtq, const u16* __restrict__ Wtk,
                                                 const u16* __restrict__ Wtv,
                                                 const float* __restrict__ bq, const float* __restrict__ bk,
                                                 const float* __restrict__ bv,
                                                 u16* __restrict__ Qo, u16* __restrict__ Ko, u16* __restrict__ Vo) {
  int z = blockIdx.z;
  const u16* X   = (z == 0) ? X1 : X2;
  const u16* Wt  = (z == 0) ? Wtq : (z == 1) ? Wtk : Wtv;
  const float* bias = (z == 0) ? bq : (z == 1) ? bk : bv;
  u16* outp = (z == 0) ? Qo : (z == 1) ? Ko : Vo;

  __shared__ __align__(16) u16 As[128 * 32];
  __shared__ __align__(16) u16 Bs[128 * 32];
  int tid = threadIdx.x;
  int m0 = blockIdx.y * 128, n0 = blockIdx.x * 128;
  int w = tid >> 6, l = tid & 63;
  int wm = w >> 1, wn = w & 1;
  f32x4 acc[4][4] = {};
  for (int kt = 0; kt < 32; ++kt) {
    #pragma unroll
    for (int c = 0; c < 2; ++c) {
      int i = c * 256 + tid;              // 0..511 int4 chunks
      int row = i >> 2, kc = i & 3;
      ((int4*)As)[i] = ((const int4*)X)[(size_t)(m0 + row) * 128 + kt * 4 + kc];
      ((int4*)Bs)[i] = ((const int4*)Wt)[(size_t)(n0 + row) * 128 + kt * 4 + kc];
    }
    __syncthreads();
    bf16x8 a[4], bb[4];
    #pragma unroll
    for (int mc = 0; mc < 4; ++mc) a[mc]  = *(const bf16x8*)&As[(wm*64 + mc*16 + (l & 15)) * 32 + (l >> 4) * 8];
    #pragma unroll
    for (int nc = 0; nc < 4; ++nc) bb[nc] = *(const bf16x8*)&Bs[(wn*64 + nc*16 + (l & 15)) * 32 + (l >> 4) * 8];
    #pragma unroll
    for (int mc = 0; mc < 4; ++mc)
      #pragma unroll
      for (int nc = 0; nc < 4; ++nc)
        acc[mc][nc] = __builtin_amdgcn_mfma_f32_16x16x32_bf16(a[mc], bb[nc], acc[mc][nc], 0, 0, 0);
    __syncthreads();
  }
  #pragma unroll
  for (int nc = 0; nc < 4; ++nc) {
    int n = n0 + wn * 64 + nc * 16 + (l & 15);
    float bvv = bias[n];
    int h = n >> 6, d = n & 63;
    #pragma unroll
    for (int mc = 0; mc < 4; ++mc) {
      int srow_base = m0 + wm * 64 + mc * 16 + (l >> 4) * 4;
      #pragma unroll
      for (int r = 0; r < 4; ++r) {
        int sm = srow_base + r;
        int b = sm >> 10, s = sm & 1023;
        outp[((size_t)((b * 16 + h) * 1024 + s)) * 64 + d] = f2bf(acc[mc][nc][r] + bvv);
      }
    }
  }
}

// ---------------- V [B,H,S,64] -> Vt [B,H,64,S] ----------------
__global__ void vtrans(const u16* __restrict__ V, u16* __restrict__ Vt) {
  __shared__ u16 T[64][65];
  int bh = blockIdx.y;
  int s0 = blockIdx.x * 64;
  int tx = threadIdx.x, ty = threadIdx.y;       // (64,4)
  #pragma unroll
  for (int j = 0; j < 16; ++j) T[ty + 4*j][tx] = V[((size_t)bh * 1024 + s0 + ty + 4*j) * 64 + tx];
  __syncthreads();
  #pragma unroll
  for (int j = 0; j < 16; ++j) Vt[((size_t)bh * 64 + ty + 4*j) * 1024 + s0 + tx] = T[tx][ty + 4*j];
}

// ---------------- fused double-softmax attention, v2 ----------------
// 16 q-rows/block, 4 waves, ~36KB LDS -> 4 blocks/CU. Scores kept in log2 domain.
// grid 8192 = 8 xcd x 16 bh x 64 qt
__global__ __launch_bounds__(256, 4) void attn2(const u16* __restrict__ Q, const u16* __restrict__ K,
                                                const u16* __restrict__ Vt, const float* __restrict__ mask,
                                                const int* __restrict__ clp, float* __restrict__ out) {
  __shared__ __align__(16) u16 sc[16 * 1024];    // 32KB swizzled scores (log2 domain); redO overlays later
  __shared__ __align__(16) u16 maskLb[1024];     // mask * log2e, bf16
  __shared__ float m1p[4][16];
  __shared__ float z1p[16][16];
  __shared__ float m1s[16];
  __shared__ float lz1[16];
  __shared__ float z2p[4][16];

  int bid = blockIdx.x;
  int xcd = bid & 7, idx = bid >> 3;
  int bh = xcd * 16 + (idx >> 6);   // 64 blocks sharing (b,h) land on one XCD -> K/V L2-resident
  int qt = idx & 63;
  int b = bh >> 4, h = bh & 15;
  int tid = threadIdx.x;
  int w = tid >> 6, l = tid & 63;
  int lq = l & 15, g = l >> 4;

  for (int i = tid; i < 1024; i += 256) maskLb[i] = f2bf(mask[b * 1024 + i] * L2E);

  const u16* Qp = Q + ((size_t)bh * 1024 + qt * 16 + lq) * 64 + g * 8;
  bf16x8 qf0 = *(const bf16x8*)Qp;
  bf16x8 qf1 = *(const bf16x8*)(Qp + 32);
  __syncthreads();

  // ---- sweep A: wave w owns keys [w*256, w*256+256); scores -> swizzled LDS (log2 domain) ----
  const u16* Kb = K + (size_t)bh * 1024 * 64;
  const float sl2e = 0.125f * L2E;
  float rmax[4] = {-1e30f, -1e30f, -1e30f, -1e30f};
  for (int t = 0; t < 16; ++t) {
    int key = w * 256 + t * 16 + lq;
    const u16* Kp = Kb + (size_t)key * 64 + g * 8;
    bf16x8 kf0 = *(const bf16x8*)Kp;
    bf16x8 kf1 = *(const bf16x8*)(Kp + 32);
    f32x4 s = {0.f, 0.f, 0.f, 0.f};
    s = __builtin_amdgcn_mfma_f32_16x16x32_bf16(qf0, kf0, s, 0, 0, 0);
    s = __builtin_amdgcn_mfma_f32_16x16x32_bf16(qf1, kf1, s, 0, 0, 0);
    float mkl = bf2f(maskLb[key]);
    #pragma unroll
    for (int r = 0; r < 4; ++r) {
      float sv = fmaf(s[r], sl2e, mkl);
      rmax[r] = fmaxf(rmax[r], sv);
      int q = g * 4 + r;
      sc[q * 1024 + (key ^ ((q & 7) << 3))] = f2bf(sv);
    }
  }
  #pragma unroll
  for (int r = 0; r < 4; ++r) {
    float v = rmax[r];
    v = fmaxf(v, __shfl_xor(v, 1));
    v = fmaxf(v, __shfl_xor(v, 2));
    v = fmaxf(v, __shfl_xor(v, 4));
    v = fmaxf(v, __shfl_xor(v, 8));
    rmax[r] = v;
  }
  if (lq == 0) {
    #pragma unroll
    for (int r = 0; r < 4; ++r) m1p[w][g * 4 + r] = rmax[r];
  }
  __syncthreads();
  if (tid < 16) m1s[tid] = fmaxf(fmaxf(m1p[0][tid], m1p[1][tid]), fmaxf(m1p[2][tid], m1p[3][tid]));
  __syncthreads();

  // ---- B1: Z1 per q row (thread = (q, 64-k chunk)) ----
  {
    int q = tid & 15, c16 = tid >> 4;
    float m1q = m1s[q];
    float z = 0.f;
    #pragma unroll
    for (int jj = 0; jj < 8; ++jj) {
      bf16x8 v = *(const bf16x8*)&sc[q * 1024 + ((c16 * 64 + jj * 8) ^ ((q & 7) << 3))];
      #pragma unroll
      for (int e = 0; e < 8; ++e) z += __builtin_amdgcn_exp2f(bf2f(v[e]) - m1q);
    }
    z1p[c16][q] = z;
  }
  __syncthreads();
  if (tid < 16) {
    float Z1 = 0.f;
    #pragma unroll
    for (int c = 0; c < 16; ++c) Z1 += z1p[c][tid];
    lz1[tid] = m1s[tid] + __builtin_amdgcn_logf(Z1);   // v_log_f32 = log2
  }
  __syncthreads();

  // ---- B2: second softmax + PV; wave w owns 64-k tiles {w, w+4, w+8, w+12} ----
  int cl = clp[0];
  const u16* Vb = Vt + (size_t)bh * 64 * 1024;
  f32x4 acc[4] = {};
  float z2 = 0.f;
  float lzq = lz1[lq];
  #pragma unroll 2
  for (int ti = 0; ti < 4; ++ti) {
    int i = ti * 4 + w;
    #pragma unroll
    for (int kc = 0; kc < 2; ++kc) {
      int keyb = i * 64 + kc * 32 + g * 8;
      bf16x8 vf0 = *(const bf16x8*)(Vb + (size_t)(0 * 16 + lq) * 1024 + keyb);
      bf16x8 vf1 = *(const bf16x8*)(Vb + (size_t)(1 * 16 + lq) * 1024 + keyb);
      bf16x8 vf2 = *(const bf16x8*)(Vb + (size_t)(2 * 16 + lq) * 1024 + keyb);
      bf16x8 vf3 = *(const bf16x8*)(Vb + (size_t)(3 * 16 + lq) * 1024 + keyb);
      bf16x8 sv = *(const bf16x8*)&sc[lq * 1024 + (keyb ^ ((lq & 7) << 3))];
      bf16x8 mkv = *(const bf16x8*)&maskLb[keyb];
      bf16x8 pf;
      if (cl) {
        #pragma unroll
        for (int e = 0; e < 8; ++e) {
          float p  = __builtin_amdgcn_exp2f(bf2f(sv[e]) - lzq);            // normalized probs1
          float p2 = __builtin_amdgcn_exp2f(fmaf(-L2E, p, bf2f(mkv[e])));  // exp(mask - p)
          z2 += p2;
          pf[e] = (short)f2bf(p2);
        }
      } else {
        #pragma unroll
        for (int e = 0; e < 8; ++e)
          pf[e] = (short)f2bf(__builtin_amdgcn_exp2f(bf2f(sv[e]) - lzq));  // already normalized
      }
      acc[0] = __builtin_amdgcn_mfma_f32_16x16x32_bf16(pf, vf0, acc[0], 0, 0, 0);
      acc[1] = __builtin_amdgcn_mfma_f32_16x16x32_bf16(pf, vf1, acc[1], 0, 0, 0);
      acc[2] = __builtin_amdgcn_mfma_f32_16x16x32_bf16(pf, vf2, acc[2], 0, 0, 0);
      acc[3] = __builtin_amdgcn_mfma_f32_16x16x32_bf16(pf, vf3, acc[3], 0, 0, 0);
    }
  }
  z2 += __shfl_xor(z2, 16);
  z2 += __shfl_xor(z2, 32);
  if (l < 16) z2p[w][l] = z2;
  __syncthreads();   // all sc reads complete -> safe to overlay redO

  float (*redO)[16][64] = (float (*)[16][64])sc;
  #pragma unroll
  for (int dc = 0; dc < 4; ++dc)
    #pragma unroll
    for (int r = 0; r < 4; ++r)
      redO[w][g * 4 + r][dc * 16 + lq] = acc[dc][r];
  __syncthreads();

  {
    int d = tid & 63, qg4 = tid >> 6;
    #pragma unroll
    for (int jj = 0; jj < 4; ++jj) {
      int q = qg4 * 4 + jj;
      float o = redO[0][q][d] + redO[1][q][d] + redO[2][q][d] + redO[3][q][d];
      float scale = cl ? __builtin_amdgcn_rcpf(z2p[0][q] + z2p[1][q] + z2p[2][q] + z2p[3][q]) : 1.0f;
      out[((size_t)(b * 1024 + qt * 16 + q)) * 1024 + h * 64 + d] = o * scale;
    }
  }
}

extern "C" void kernel_launch(void* const* d_in, const int* in_sizes, int n_in,
                              void* d_out, int out_size, void* d_ws, size_t ws_size,
                              hipStream_t stream) {
  const float* s1   = (const float*)d_in[0];
  const float* s2   = (const float*)d_in[1];
  const float* mask = (const float*)d_in[2];
  const float* Wq   = (const float*)d_in[3];
  const float* bq   = (const float*)d_in[4];
  const float* Wk   = (const float*)d_in[5];
  const float* bk   = (const float*)d_in[6];
  const float* Wv   = (const float*)d_in[7];
  const float* bv   = (const float*)d_in[8];
  const int*   cl   = (const int*)d_in[9];
  float* out = (float*)d_out;

  // ws layout (u16 elements): X1[8M] X2[8M] Wtq[1M] Wtk[1M] Wtv[1M] Q[8M] K[8M] V[8M]
  u16* ws  = (u16*)d_ws;
  const size_t M1 = 1024 * 1024;
  u16* X1  = ws;
  u16* X2  = ws + 8 * M1;
  u16* Wtq = ws + 16 * M1;
  u16* Wtk = Wtq + M1;
  u16* Wtv = Wtk + M1;
  u16* Qb  = Wtv + M1;
  u16* Kb  = Qb + 8 * M1;
  u16* Vb  = Kb + 8 * M1;
  u16* Vtb = X1;   // alias: X1 is dead after the projections dispatch completes

  conv_f32_bf16<<<2048, 256, 0, stream>>>(s1, X1, 2097152);
  conv_f32_bf16<<<2048, 256, 0, stream>>>(s2, X2, 2097152);
  dim3 wtb(32, 8);
  wtrans<<<dim3(32, 32), wtb, 0, stream>>>(Wq, Wtq);
  wtrans<<<dim3(32, 32), wtb, 0, stream>>>(Wk, Wtk);
  wtrans<<<dim3(32, 32), wtb, 0, stream>>>(Wv, Wtv);
  qkv_gemm3<<<dim3(8, 64, 3), 256, 0, stream>>>(X1, X2, Wtq, Wtk, Wtv, bq, bk, bv, Qb, Kb, Vb);
  vtrans<<<dim3(16, 128), dim3(64, 4), 0, stream>>>(Vb, Vtb);
  attn2<<<8192, 256, 0, stream>>>(Qb, Kb, Vtb, mask, cl, out);
}

// Round 3
// 337.747 us; speedup vs baseline: 1.1254x; 1.0496x over previous
//
#include <hip/hip_runtime.h>

typedef unsigned short u16;
typedef __attribute__((ext_vector_type(8))) short bf16x8;   // 8 bf16 = 4 VGPRs (MFMA A/B frag)
typedef __attribute__((ext_vector_type(4))) float f32x4;    // MFMA C/D frag

#define L2E 1.4426950408889634f

__device__ __forceinline__ u16 f2bf(float f) {
  unsigned u = __float_as_uint(f);
  u = u + 0x7fffu + ((u >> 16) & 1u);   // RNE
  return (u16)(u >> 16);
}
__device__ __forceinline__ float bf2f(short s) {
  return __uint_as_float(((unsigned)(u16)s) << 16);
}

// ---------------- prep: f32 -> bf16 elementwise ----------------
__global__ void conv_f32_bf16(const float* __restrict__ in, u16* __restrict__ out, int n4) {
  int i = blockIdx.x * blockDim.x + threadIdx.x;
  int stride = gridDim.x * blockDim.x;
  for (; i < n4; i += stride) {
    float4 v = ((const float4*)in)[i];
    ushort4 o = make_ushort4(f2bf(v.x), f2bf(v.y), f2bf(v.z), f2bf(v.w));
    ((ushort4*)out)[i] = o;
  }
}

// ---------------- prep: W[k][n] f32 -> Wt[n][k] bf16 ----------------
__global__ void wtrans(const float* __restrict__ W, u16* __restrict__ Wt) {
  __shared__ float T[32][33];
  int k0 = blockIdx.y * 32, n0 = blockIdx.x * 32;
  int tx = threadIdx.x, ty = threadIdx.y;       // (32,8)
  #pragma unroll
  for (int j = 0; j < 4; ++j) T[ty + 8*j][tx] = W[(size_t)(k0 + ty + 8*j) * 1024 + n0 + tx];
  __syncthreads();
  #pragma unroll
  for (int j = 0; j < 4; ++j) Wt[(size_t)(n0 + ty + 8*j) * 1024 + k0 + tx] = f2bf(T[tx][ty + 8*j]);
}

// ---------------- QKV projection GEMM (3 fused via blockIdx.z), global_load_lds staging ----------------
__global__ __launch_bounds__(256) void qkv_gemm3(const u16* __restrict__ X1, const u16* __restrict__ X2,
                                                 const u16* __restrict__ Wtq, const u16* __restrict__ Wtk,
                                                 const u16* __restrict__ Wtv,
                                                 const float* __restrict__ bq, const float* __restrict__ bk,
                                                 const float* __restrict__ bv,
                                                 u16* __restrict__ Qo, u16* __restrict__ Ko, u16* __restrict__ Vo) {
  int z = blockIdx.z;
  const u16* X   = (z == 0) ? X1 : X2;
  const u16* Wt  = (z == 0) ? Wtq : (z == 1) ? Wtk : Wtv;
  const float* bias = (z == 0) ? bq : (z == 1) ? bk : bv;
  u16* outp = (z == 0) ? Qo : (z == 1) ? Ko : Vo;

  __shared__ __align__(16) u16 As[128 * 32];
  __shared__ __align__(16) u16 Bs[128 * 32];
  int tid = threadIdx.x;
  int m0 = blockIdx.y * 128, n0 = blockIdx.x * 128;
  int w = tid >> 6, l = tid & 63;
  int wm = w >> 1, wn = w & 1;
  const int4* Xs = (const int4*)X;
  const int4* Ws = (const int4*)Wt;
  int4* As4 = (int4*)As;
  int4* Bs4 = (int4*)Bs;
  f32x4 acc[4][4] = {};
  for (int kt = 0; kt < 32; ++kt) {
    #pragma unroll
    for (int c = 0; c < 2; ++c) {
      int i = c * 256 + tid;              // 0..511 int4 chunks; dest = wave-uniform base + lane*16
      int row = i >> 2, kc = i & 3;
      __builtin_amdgcn_global_load_lds(
          (const __attribute__((address_space(1))) void*)&Xs[(size_t)(m0 + row) * 128 + kt * 4 + kc],
          (__attribute__((address_space(3))) void*)&As4[i], 16, 0, 0);
      __builtin_amdgcn_global_load_lds(
          (const __attribute__((address_space(1))) void*)&Ws[(size_t)(n0 + row) * 128 + kt * 4 + kc],
          (__attribute__((address_space(3))) void*)&Bs4[i], 16, 0, 0);
    }
    __syncthreads();
    bf16x8 a[4], bb[4];
    #pragma unroll
    for (int mc = 0; mc < 4; ++mc) a[mc]  = *(const bf16x8*)&As[(wm*64 + mc*16 + (l & 15)) * 32 + (l >> 4) * 8];
    #pragma unroll
    for (int nc = 0; nc < 4; ++nc) bb[nc] = *(const bf16x8*)&Bs[(wn*64 + nc*16 + (l & 15)) * 32 + (l >> 4) * 8];
    #pragma unroll
    for (int mc = 0; mc < 4; ++mc)
      #pragma unroll
      for (int nc = 0; nc < 4; ++nc)
        acc[mc][nc] = __builtin_amdgcn_mfma_f32_16x16x32_bf16(a[mc], bb[nc], acc[mc][nc], 0, 0, 0);
    __syncthreads();
  }
  #pragma unroll
  for (int nc = 0; nc < 4; ++nc) {
    int n = n0 + wn * 64 + nc * 16 + (l & 15);
    float bvv = bias[n];
    int h = n >> 6, d = n & 63;
    #pragma unroll
    for (int mc = 0; mc < 4; ++mc) {
      int srow_base = m0 + wm * 64 + mc * 16 + (l >> 4) * 4;
      #pragma unroll
      for (int r = 0; r < 4; ++r) {
        int sm = srow_base + r;
        int b = sm >> 10, s = sm & 1023;
        outp[((size_t)((b * 16 + h) * 1024 + s)) * 64 + d] = f2bf(acc[mc][nc][r] + bvv);
      }
    }
  }
}

// ---------------- V [B,H,S,64] -> Vt [B,H,64,S] ----------------
__global__ void vtrans(const u16* __restrict__ V, u16* __restrict__ Vt) {
  __shared__ u16 T[64][65];
  int bh = blockIdx.y;
  int s0 = blockIdx.x * 64;
  int tx = threadIdx.x, ty = threadIdx.y;       // (64,4)
  #pragma unroll
  for (int j = 0; j < 16; ++j) T[ty + 4*j][tx] = V[((size_t)bh * 1024 + s0 + ty + 4*j) * 64 + tx];
  __syncthreads();
  #pragma unroll
  for (int j = 0; j < 16; ++j) Vt[((size_t)bh * 64 + ty + 4*j) * 1024 + s0 + tx] = T[tx][ty + 4*j];
}

// ---------------- fused double-softmax attention, v3 ----------------
// Swapped QK^T (S^T = mfma(K,Q)): lane owns q-row = lane&15, keys {c*16+g*4+r} in regs.
// E = exp2(s-m1) stored bf16 in swizzled LDS once; B2 re-reads as PV A-frags.
// grid 8192 = 8 xcd x 16 bh x 64 qt; 4 waves, wave w owns keys [w*256, w*256+256).
__global__ __launch_bounds__(256, 4) void attn3(const u16* __restrict__ Q, const u16* __restrict__ K,
                                                const u16* __restrict__ Vt, const float* __restrict__ mask,
                                                const int* __restrict__ clp, float* __restrict__ out) {
  __shared__ __align__(16) u16 sc[16 * 1024];    // 32KB swizzled E (bf16); redO overlays later
  __shared__ __align__(16) float maskL2[1024];   // mask * log2e, f32
  __shared__ float m1p[4][16];
  __shared__ float z1p[4][16];
  __shared__ float s1i[16];
  __shared__ float z2p[4][16];

  int bid = blockIdx.x;
  int xcd = bid & 7, idx = bid >> 3;
  int bh = xcd * 16 + (idx >> 6);   // 64 blocks sharing (b,h) per XCD -> K/V L2-resident
  int qt = idx & 63;
  int b = bh >> 4, h = bh & 15;
  int tid = threadIdx.x;
  int w = tid >> 6, l = tid & 63;
  int lq = l & 15, g = l >> 4;
  int swz = (lq & 7) << 3;

  for (int i = tid; i < 1024; i += 256) maskL2[i] = mask[b * 1024 + i] * L2E;

  const u16* Qp = Q + ((size_t)bh * 1024 + qt * 16 + lq) * 64 + g * 8;
  bf16x8 qf0 = *(const bf16x8*)Qp;
  bf16x8 qf1 = *(const bf16x8*)(Qp + 32);
  __syncthreads();

  // ---- sweep A: swapped QK^T into registers ----
  const u16* Kb = K + (size_t)bh * 65536;
  const float sl2e = 0.125f * L2E;
  f32x4 s[16];
  float rmax = -1e30f;
  #pragma unroll
  for (int c = 0; c < 16; ++c) {
    int krow = w * 256 + c * 16 + lq;
    const u16* Kp = Kb + (size_t)krow * 64 + g * 8;
    bf16x8 kf0 = *(const bf16x8*)Kp;
    bf16x8 kf1 = *(const bf16x8*)(Kp + 32);
    f32x4 t = {0.f, 0.f, 0.f, 0.f};
    t = __builtin_amdgcn_mfma_f32_16x16x32_bf16(kf0, qf0, t, 0, 0, 0);
    t = __builtin_amdgcn_mfma_f32_16x16x32_bf16(kf1, qf1, t, 0, 0, 0);
    float4 mk = *(const float4*)&maskL2[w * 256 + c * 16 + g * 4];
    s[c][0] = fmaf(t[0], sl2e, mk.x);
    s[c][1] = fmaf(t[1], sl2e, mk.y);
    s[c][2] = fmaf(t[2], sl2e, mk.z);
    s[c][3] = fmaf(t[3], sl2e, mk.w);
    rmax = fmaxf(rmax, fmaxf(fmaxf(s[c][0], s[c][1]), fmaxf(s[c][2], s[c][3])));
  }
  rmax = fmaxf(rmax, __shfl_xor(rmax, 16));
  rmax = fmaxf(rmax, __shfl_xor(rmax, 32));
  if (l < 16) m1p[w][l] = rmax;
  __syncthreads();
  float m1 = fmaxf(fmaxf(m1p[0][lq], m1p[1][lq]), fmaxf(m1p[2][lq], m1p[3][lq]));

  // ---- E = exp2(s - m1) in regs; Z1 partial; pack to LDS ----
  float z1 = 0.f;
  #pragma unroll
  for (int c = 0; c < 16; ++c) {
    #pragma unroll
    for (int r = 0; r < 4; ++r) {
      float e = __builtin_amdgcn_exp2f(s[c][r] - m1);
      s[c][r] = e;
      z1 += e;
    }
  }
  z1 += __shfl_xor(z1, 16);
  z1 += __shfl_xor(z1, 32);
  if (l < 16) z1p[w][l] = z1;
  #pragma unroll
  for (int c = 0; c < 16; ++c) {
    unsigned p0 = ((unsigned)f2bf(s[c][1]) << 16) | f2bf(s[c][0]);
    unsigned p1 = ((unsigned)f2bf(s[c][3]) << 16) | f2bf(s[c][2]);
    int key4 = w * 256 + c * 16 + g * 4;
    uint2 pk; pk.x = p0; pk.y = p1;
    *(uint2*)&sc[lq * 1024 + (key4 ^ swz)] = pk;
  }
  __syncthreads();
  float Z1 = z1p[0][lq] + z1p[1][lq] + z1p[2][lq] + z1p[3][lq];
  float cr = L2E * __builtin_amdgcn_rcpf(Z1);
  if (tid < 16) s1i[tid] = __builtin_amdgcn_rcpf(Z1);   // w==0 lanes: lq==tid

  // ---- B2: p2 = exp2(mkl - cr*E) + PV over wave's key quarter ----
  int cl = clp[0];
  const u16* Vb = Vt + (size_t)bh * 65536;
  f32x4 acc[4] = {};
  float z2 = 0.f;
  #pragma unroll 2
  for (int t = 0; t < 8; ++t) {
    int kb8 = w * 256 + t * 32 + g * 8;
    bf16x8 ef = *(const bf16x8*)&sc[lq * 1024 + (kb8 ^ swz)];
    bf16x8 pf;
    if (cl) {
      float4 mk0 = *(const float4*)&maskL2[kb8];
      float4 mk1 = *(const float4*)&maskL2[kb8 + 4];
      float mkv[8] = {mk0.x, mk0.y, mk0.z, mk0.w, mk1.x, mk1.y, mk1.z, mk1.w};
      #pragma unroll
      for (int e = 0; e < 8; ++e) {
        float p2 = __builtin_amdgcn_exp2f(fmaf(-cr, bf2f(ef[e]), mkv[e]));
        z2 += p2;
        pf[e] = (short)f2bf(p2);
      }
    } else {
      pf = ef;   // unnormalized E; scaled by 1/Z1 at the end
    }
    bf16x8 vf0 = *(const bf16x8*)(Vb + (size_t)(0 * 16 + lq) * 1024 + kb8);
    bf16x8 vf1 = *(const bf16x8*)(Vb + (size_t)(1 * 16 + lq) * 1024 + kb8);
    bf16x8 vf2 = *(const bf16x8*)(Vb + (size_t)(2 * 16 + lq) * 1024 + kb8);
    bf16x8 vf3 = *(const bf16x8*)(Vb + (size_t)(3 * 16 + lq) * 1024 + kb8);
    acc[0] = __builtin_amdgcn_mfma_f32_16x16x32_bf16(pf, vf0, acc[0], 0, 0, 0);
    acc[1] = __builtin_amdgcn_mfma_f32_16x16x32_bf16(pf, vf1, acc[1], 0, 0, 0);
    acc[2] = __builtin_amdgcn_mfma_f32_16x16x32_bf16(pf, vf2, acc[2], 0, 0, 0);
    acc[3] = __builtin_amdgcn_mfma_f32_16x16x32_bf16(pf, vf3, acc[3], 0, 0, 0);
  }
  z2 += __shfl_xor(z2, 16);
  z2 += __shfl_xor(z2, 32);
  if (l < 16) z2p[w][l] = z2;
  __syncthreads();   // sc reads done -> overlay redO

  float (*redO)[16][64] = (float (*)[16][64])sc;
  #pragma unroll
  for (int dc = 0; dc < 4; ++dc)
    #pragma unroll
    for (int r = 0; r < 4; ++r)
      redO[w][g * 4 + r][dc * 16 + lq] = acc[dc][r];
  __syncthreads();

  {
    int d = tid & 63, q0 = tid >> 6;
    #pragma unroll
    for (int jj = 0; jj < 4; ++jj) {
      int q = q0 * 4 + jj;
      float o = redO[0][q][d] + redO[1][q][d] + redO[2][q][d] + redO[3][q][d];
      float scale = cl ? __builtin_amdgcn_rcpf(z2p[0][q] + z2p[1][q] + z2p[2][q] + z2p[3][q]) : s1i[q];
      out[((size_t)(b * 1024 + qt * 16 + q)) * 1024 + h * 64 + d] = o * scale;
    }
  }
}

extern "C" void kernel_launch(void* const* d_in, const int* in_sizes, int n_in,
                              void* d_out, int out_size, void* d_ws, size_t ws_size,
                              hipStream_t stream) {
  const float* s1   = (const float*)d_in[0];
  const float* s2   = (const float*)d_in[1];
  const float* mask = (const float*)d_in[2];
  const float* Wq   = (const float*)d_in[3];
  const float* bq   = (const float*)d_in[4];
  const float* Wk   = (const float*)d_in[5];
  const float* bk   = (const float*)d_in[6];
  const float* Wv   = (const float*)d_in[7];
  const float* bv   = (const float*)d_in[8];
  const int*   cl   = (const int*)d_in[9];
  float* out = (float*)d_out;

  // ws layout (u16 elements): X1[8M] X2[8M] Wtq[1M] Wtk[1M] Wtv[1M] Q[8M] K[8M] V[8M]
  u16* ws  = (u16*)d_ws;
  const size_t M1 = 1024 * 1024;
  u16* X1  = ws;
  u16* X2  = ws + 8 * M1;
  u16* Wtq = ws + 16 * M1;
  u16* Wtk = Wtq + M1;
  u16* Wtv = Wtk + M1;
  u16* Qb  = Wtv + M1;
  u16* Kb  = Qb + 8 * M1;
  u16* Vb  = Kb + 8 * M1;
  u16* Vtb = X1;   // alias: X1 is dead after the projections dispatch completes

  conv_f32_bf16<<<2048, 256, 0, stream>>>(s1, X1, 2097152);
  conv_f32_bf16<<<2048, 256, 0, stream>>>(s2, X2, 2097152);
  dim3 wtb(32, 8);
  wtrans<<<dim3(32, 32), wtb, 0, stream>>>(Wq, Wtq);
  wtrans<<<dim3(32, 32), wtb, 0, stream>>>(Wk, Wtk);
  wtrans<<<dim3(32, 32), wtb, 0, stream>>>(Wv, Wtv);
  qkv_gemm3<<<dim3(8, 64, 3), 256, 0, stream>>>(X1, X2, Wtq, Wtk, Wtv, bq, bk, bv, Qb, Kb, Vb);
  vtrans<<<dim3(16, 128), dim3(64, 4), 0, stream>>>(Vb, Vtb);
  attn3<<<8192, 256, 0, stream>>>(Qb, Kb, Vtb, mask, cl, out);
}

// Round 4
// 293.169 us; speedup vs baseline: 1.2965x; 1.1521x over previous
//
#include <hip/hip_runtime.h>
#include <hip/hip_bf16.h>

typedef unsigned short u16;
typedef __attribute__((ext_vector_type(8))) short bf16x8;   // 8 bf16 = 4 VGPRs (MFMA A/B frag)
typedef __attribute__((ext_vector_type(4))) float f32x4;    // MFMA C/D frag
typedef __attribute__((ext_vector_type(4))) unsigned u32x4;

#define L2E 1.4426950408889634f

__device__ __forceinline__ u16 f2bf(float f) {
  unsigned u = __float_as_uint(f);
  u = u + 0x7fffu + ((u >> 16) & 1u);   // RNE
  return (u16)(u >> 16);
}
__device__ __forceinline__ float bf2f(short s) {
  return __uint_as_float(((unsigned)(u16)s) << 16);
}
__device__ __forceinline__ unsigned pkbf(float a, float b) {   // low = a, high = b (RNE)
  return ((unsigned)f2bf(b) << 16) | f2bf(a);
}
__device__ __forceinline__ float lo16(unsigned v) { return __uint_as_float(v << 16); }
__device__ __forceinline__ float hi16(unsigned v) { return __uint_as_float(v & 0xffff0000u); }

// ---------------- prep: f32 -> bf16 elementwise ----------------
__global__ void conv_f32_bf16(const float* __restrict__ in, u16* __restrict__ out, int n4) {
  int i = blockIdx.x * blockDim.x + threadIdx.x;
  int stride = gridDim.x * blockDim.x;
  for (; i < n4; i += stride) {
    float4 v = ((const float4*)in)[i];
    ushort4 o = make_ushort4(f2bf(v.x), f2bf(v.y), f2bf(v.z), f2bf(v.w));
    ((ushort4*)out)[i] = o;
  }
}

// ---------------- prep: W[k][n] f32 -> Wt[n][k] bf16 ----------------
__global__ void wtrans(const float* __restrict__ W, u16* __restrict__ Wt) {
  __shared__ float T[32][33];
  int k0 = blockIdx.y * 32, n0 = blockIdx.x * 32;
  int tx = threadIdx.x, ty = threadIdx.y;       // (32,8)
  #pragma unroll
  for (int j = 0; j < 4; ++j) T[ty + 8*j][tx] = W[(size_t)(k0 + ty + 8*j) * 1024 + n0 + tx];
  __syncthreads();
  #pragma unroll
  for (int j = 0; j < 4; ++j) Wt[(size_t)(n0 + ty + 8*j) * 1024 + k0 + tx] = f2bf(T[tx][ty + 8*j]);
}

// ---------------- QKV projection GEMM (3 fused via blockIdx.z), global_load_lds staging ----------------
__global__ __launch_bounds__(256) void qkv_gemm3(const u16* __restrict__ X1, const u16* __restrict__ X2,
                                                 const u16* __restrict__ Wtq, const u16* __restrict__ Wtk,
                                                 const u16* __restrict__ Wtv,
                                                 const float* __restrict__ bq, const float* __restrict__ bk,
                                                 const float* __restrict__ bv,
                                                 u16* __restrict__ Qo, u16* __restrict__ Ko, u16* __restrict__ Vo) {
  int z = blockIdx.z;
  const u16* X   = (z == 0) ? X1 : X2;
  const u16* Wt  = (z == 0) ? Wtq : (z == 1) ? Wtk : Wtv;
  const float* bias = (z == 0) ? bq : (z == 1) ? bk : bv;
  u16* outp = (z == 0) ? Qo : (z == 1) ? Ko : Vo;

  __shared__ __align__(16) u16 As[128 * 32];
  __shared__ __align__(16) u16 Bs[128 * 32];
  int tid = threadIdx.x;
  int m0 = blockIdx.y * 128, n0 = blockIdx.x * 128;
  int w = tid >> 6, l = tid & 63;
  int wm = w >> 1, wn = w & 1;
  const int4* Xs = (const int4*)X;
  const int4* Ws = (const int4*)Wt;
  int4* As4 = (int4*)As;
  int4* Bs4 = (int4*)Bs;
  f32x4 acc[4][4] = {};
  for (int kt = 0; kt < 32; ++kt) {
    #pragma unroll
    for (int c = 0; c < 2; ++c) {
      int i = c * 256 + tid;              // 0..511 int4 chunks; dest = wave-uniform base + lane*16
      int row = i >> 2, kc = i & 3;
      __builtin_amdgcn_global_load_lds(
          (const __attribute__((address_space(1))) void*)&Xs[(size_t)(m0 + row) * 128 + kt * 4 + kc],
          (__attribute__((address_space(3))) void*)&As4[i], 16, 0, 0);
      __builtin_amdgcn_global_load_lds(
          (const __attribute__((address_space(1))) void*)&Ws[(size_t)(n0 + row) * 128 + kt * 4 + kc],
          (__attribute__((address_space(3))) void*)&Bs4[i], 16, 0, 0);
    }
    __syncthreads();
    bf16x8 a[4], bb[4];
    #pragma unroll
    for (int mc = 0; mc < 4; ++mc) a[mc]  = *(const bf16x8*)&As[(wm*64 + mc*16 + (l & 15)) * 32 + (l >> 4) * 8];
    #pragma unroll
    for (int nc = 0; nc < 4; ++nc) bb[nc] = *(const bf16x8*)&Bs[(wn*64 + nc*16 + (l & 15)) * 32 + (l >> 4) * 8];
    #pragma unroll
    for (int mc = 0; mc < 4; ++mc)
      #pragma unroll
      for (int nc = 0; nc < 4; ++nc)
        acc[mc][nc] = __builtin_amdgcn_mfma_f32_16x16x32_bf16(a[mc], bb[nc], acc[mc][nc], 0, 0, 0);
    __syncthreads();
  }
  #pragma unroll
  for (int nc = 0; nc < 4; ++nc) {
    int n = n0 + wn * 64 + nc * 16 + (l & 15);
    float bvv = bias[n];
    int h = n >> 6, d = n & 63;
    #pragma unroll
    for (int mc = 0; mc < 4; ++mc) {
      int srow_base = m0 + wm * 64 + mc * 16 + (l >> 4) * 4;
      #pragma unroll
      for (int r = 0; r < 4; ++r) {
        int sm = srow_base + r;
        int b = sm >> 10, s = sm & 1023;
        outp[((size_t)((b * 16 + h) * 1024 + s)) * 64 + d] = f2bf(acc[mc][nc][r] + bvv);
      }
    }
  }
}

// ---------------- V [B,H,S,64] -> Vt [B,H,64,S] ----------------
__global__ void vtrans(const u16* __restrict__ V, u16* __restrict__ Vt) {
  __shared__ u16 T[64][65];
  int bh = blockIdx.y;
  int s0 = blockIdx.x * 64;
  int tx = threadIdx.x, ty = threadIdx.y;       // (64,4)
  #pragma unroll
  for (int j = 0; j < 16; ++j) T[ty + 4*j][tx] = V[((size_t)bh * 1024 + s0 + ty + 4*j) * 64 + tx];
  __syncthreads();
  #pragma unroll
  for (int j = 0; j < 16; ++j) Vt[((size_t)bh * 64 + ty + 4*j) * 1024 + s0 + tx] = T[tx][ty + 4*j];
}

// ---------------- fused double-softmax attention, v5 ----------------
// 4 waves x 16 q-rows; each wave owns its q-rows against ALL 1024 keys.
// Key order permuted per 32-chunk (slot sigma -> key kappa: bit-rotate) so the
// swapped-MFMA C-layout register file IS the PV A-fragment layout. Scores/E live
// entirely in 128 VGPRs; softmax reductions are in-lane + shfl. K/V staged via
// global_load_lds (pre-swizzled source -> conflict-floor LDS reads), depth-1 dbuf.
// grid 2048 = 8 xcd x 16 bh x 16 qt; LDS 48KB; 2 blocks/CU.
__global__ __launch_bounds__(256, 2) void attn5(const u16* __restrict__ Q, const u16* __restrict__ K,
                                                const u16* __restrict__ Vt, const float* __restrict__ mask,
                                                const int* __restrict__ clp, float* __restrict__ out) {
  __shared__ __align__(16) u16 Kl[2][128 * 64];   // 2 x 16KB : 128-key K tiles
  __shared__ __align__(16) u16 Vl[2][64 * 64];    // 2 x 8KB  : 64-key V tiles (64 d-rows)

  int bid = blockIdx.x;
  int xcd = bid & 7, idx = bid >> 3;
  int bh = xcd * 16 + (idx >> 4);   // 16 q-tile blocks share (b,h) within an XCD
  int qt = idx & 15;
  int b = bh >> 4, h = bh & 15;
  int tid = threadIdx.x;
  int w = tid >> 6, l = tid & 63;
  int lq = l & 15, g = l >> 4;
  int qb = qt * 64 + w * 16;

  const float* mrow = mask + b * 1024;
  const u16* Kb = K + (size_t)bh * 65536;
  const u16* Vb = Vt + (size_t)bh * 65536;
  int cl = clp[0];

  // K stage: dest chunk i=(row,ch of 8); src chunk = ch ^ F(row), F = (row&3)|(((row>>3 ^ row>>4)&1)<<2)
#define STAGE_K(bi, t) do {                                                                  \
    _Pragma("unroll")                                                                        \
    for (int c_ = 0; c_ < 4; ++c_) {                                                         \
      int i_ = c_ * 256 + tid; int row_ = i_ >> 3, ch_ = i_ & 7;                             \
      int f_ = (row_ & 3) | ((((row_ >> 3) ^ (row_ >> 4)) & 1) << 2);                        \
      __builtin_amdgcn_global_load_lds(                                                      \
        (const __attribute__((address_space(1))) void*)(Kb + (size_t)((t) * 128 + row_) * 64 + ((ch_ ^ f_) * 8)), \
        (__attribute__((address_space(3))) void*)&Kl[bi][i_ * 8], 16, 0, 0);                 \
    } } while (0)

  // V stage (64-key tile): row=d (0..63, 8 chunks of 8 keys); src chunk = ch ^ (row&7)
#define STAGE_V(bi, t) do {                                                                  \
    _Pragma("unroll")                                                                        \
    for (int c_ = 0; c_ < 2; ++c_) {                                                         \
      int i_ = c_ * 256 + tid; int row_ = i_ >> 3, ch_ = i_ & 7;                             \
      __builtin_amdgcn_global_load_lds(                                                      \
        (const __attribute__((address_space(1))) void*)(Vb + (size_t)row_ * 1024 + (t) * 64 + ((ch_ ^ (row_ & 7)) * 8)), \
        (__attribute__((address_space(3))) void*)&Vl[bi][i_ * 8], 16, 0, 0);                 \
    } } while (0)

  STAGE_K(0, 0);

  const u16* Qp = Q + ((size_t)bh * 1024 + qb + lq) * 64 + g * 8;
  bf16x8 qf0 = *(const bf16x8*)Qp;
  bf16x8 qf1 = *(const bf16x8*)(Qp + 32);

  __syncthreads();   // K0 staged

  // ---- pass A: swapped QK^T over 8 K-tiles; scores bf16-packed into sp[128] ----
  const float sl2e = 0.125f * L2E;
  unsigned sp[128];
  float rmax = -1e30f;
  int cur = 0;
  #pragma unroll
  for (int t = 0; t < 8; ++t) {
    if (t < 7) STAGE_K(cur ^ 1, t + 1);
    else       STAGE_V(0, 0);
    #pragma unroll
    for (int ct = 0; ct < 8; ++ct) {
      int m = ct >> 1, c = ct & 1;
      int krow = m * 32 + ((lq >> 2) << 3) + c * 4 + (lq & 3);   // kappa(sigma = ct*16+lq)
      int F = (krow & 3) | ((((krow >> 3) ^ (krow >> 4)) & 1) << 2);
      const u16* kp0 = &Kl[cur][krow * 64 + ((g ^ F) * 8)];
      const u16* kp1 = &Kl[cur][krow * 64 + (((g + 4) ^ F) * 8)];
      bf16x8 kf0 = *(const bf16x8*)kp0;
      bf16x8 kf1 = *(const bf16x8*)kp1;
      f32x4 tt = {0.f, 0.f, 0.f, 0.f};
      tt = __builtin_amdgcn_mfma_f32_16x16x32_bf16(kf0, qf0, tt, 0, 0, 0);
      tt = __builtin_amdgcn_mfma_f32_16x16x32_bf16(kf1, qf1, tt, 0, 0, 0);
      // lane (g,lq): C slot sigma = ct*16 + g*4 + r -> actual key t*128 + m*32 + g*8 + c*4 + r
      float4 mk = *(const float4*)(mrow + t * 128 + m * 32 + g * 8 + c * 4);
      float s0 = fmaf(tt[0], sl2e, mk.x * L2E);
      float s1 = fmaf(tt[1], sl2e, mk.y * L2E);
      float s2 = fmaf(tt[2], sl2e, mk.z * L2E);
      float s3 = fmaf(tt[3], sl2e, mk.w * L2E);
      rmax = fmaxf(rmax, fmaxf(fmaxf(s0, s1), fmaxf(s2, s3)));
      sp[t * 16 + m * 4 + c * 2 + 0] = pkbf(s0, s1);
      sp[t * 16 + m * 4 + c * 2 + 1] = pkbf(s2, s3);
    }
    __syncthreads();
    cur ^= 1;
  }

  // ---- softmax-1: m1, E = exp2(s-m1), Z1 (all in regs; wave owns full rows) ----
  rmax = fmaxf(rmax, __shfl_xor(rmax, 16));
  rmax = fmaxf(rmax, __shfl_xor(rmax, 32));
  float m1 = rmax;
  float z1 = 0.f;
  #pragma unroll
  for (int i = 0; i < 128; ++i) {
    unsigned v = sp[i];
    float e0 = __builtin_amdgcn_exp2f(lo16(v) - m1);
    float e1 = __builtin_amdgcn_exp2f(hi16(v) - m1);
    z1 += e0 + e1;
    sp[i] = pkbf(e0, e1);
  }
  z1 += __shfl_xor(z1, 16);
  z1 += __shfl_xor(z1, 32);
  float iz1 = __builtin_amdgcn_rcpf(z1);
  float cr = L2E * iz1;

  // ---- pass B: p2 = exp2(mask*L2E - cr*E), PV over 16 V-tiles of 64 keys ----
  f32x4 acc[4] = {};
  float z2 = 0.f;
  #pragma unroll
  for (int t = 0; t < 16; ++t) {
    if (t < 15) STAGE_V((t + 1) & 1, t + 1);
    #pragma unroll
    for (int mm = 0; mm < 2; ++mm) {
      int M = t * 2 + mm;                       // global 32-key chunk
      bf16x8 pf;
      if (cl) {
        float4 mk0 = *(const float4*)(mrow + M * 32 + g * 8);
        float4 mk1 = *(const float4*)(mrow + M * 32 + g * 8 + 4);
        unsigned e01 = sp[M * 4 + 0], e23 = sp[M * 4 + 1];
        unsigned e45 = sp[M * 4 + 2], e67 = sp[M * 4 + 3];
        float p0 = __builtin_amdgcn_exp2f(fmaf(mk0.x, L2E, -cr * lo16(e01)));
        float p1 = __builtin_amdgcn_exp2f(fmaf(mk0.y, L2E, -cr * hi16(e01)));
        float p2 = __builtin_amdgcn_exp2f(fmaf(mk0.z, L2E, -cr * lo16(e23)));
        float p3 = __builtin_amdgcn_exp2f(fmaf(mk0.w, L2E, -cr * hi16(e23)));
        float p4 = __builtin_amdgcn_exp2f(fmaf(mk1.x, L2E, -cr * lo16(e45)));
        float p5 = __builtin_amdgcn_exp2f(fmaf(mk1.y, L2E, -cr * hi16(e45)));
        float p6 = __builtin_amdgcn_exp2f(fmaf(mk1.z, L2E, -cr * lo16(e67)));
        float p7 = __builtin_amdgcn_exp2f(fmaf(mk1.w, L2E, -cr * hi16(e67)));
        z2 += ((p0 + p1) + (p2 + p3)) + ((p4 + p5) + (p6 + p7));
        u32x4 pk = {pkbf(p0, p1), pkbf(p2, p3), pkbf(p4, p5), pkbf(p6, p7)};
        pf = __builtin_bit_cast(bf16x8, pk);
      } else {
        u32x4 pk = {sp[M * 4 + 0], sp[M * 4 + 1], sp[M * 4 + 2], sp[M * 4 + 3]};
        pf = __builtin_bit_cast(bf16x8, pk);
      }
      #pragma unroll
      for (int dc = 0; dc < 4; ++dc) {
        int row = dc * 16 + lq;
        int ch = ((mm * 4 + g) ^ (row & 7));
        bf16x8 vf = *(const bf16x8*)&Vl[t & 1][row * 64 + ch * 8];
        acc[dc] = __builtin_amdgcn_mfma_f32_16x16x32_bf16(pf, vf, acc[dc], 0, 0, 0);
      }
    }
    __syncthreads();
  }

  // ---- epilogue: scale by 1/Z2 (cl) or 1/Z1; redistribute via shfl ----
  z2 += __shfl_xor(z2, 16);
  z2 += __shfl_xor(z2, 32);
  float phi = cl ? __builtin_amdgcn_rcpf(z2) : iz1;
  #pragma unroll
  for (int r = 0; r < 4; ++r) {
    float ph = __shfl(phi, g * 4 + r);   // phi of q-row g*4+r (held at lane g*4+r)
    size_t orow = ((size_t)(b * 1024 + qb + g * 4 + r)) * 1024 + h * 64;
    #pragma unroll
    for (int dc = 0; dc < 4; ++dc)
      out[orow + dc * 16 + lq] = acc[dc][r] * ph;
  }
#undef STAGE_K
#undef STAGE_V
}

extern "C" void kernel_launch(void* const* d_in, const int* in_sizes, int n_in,
                              void* d_out, int out_size, void* d_ws, size_t ws_size,
                              hipStream_t stream) {
  const float* s1   = (const float*)d_in[0];
  const float* s2   = (const float*)d_in[1];
  const float* mask = (const float*)d_in[2];
  const float* Wq   = (const float*)d_in[3];
  const float* bq   = (const float*)d_in[4];
  const float* Wk   = (const float*)d_in[5];
  const float* bk   = (const float*)d_in[6];
  const float* Wv   = (const float*)d_in[7];
  const float* bv   = (const float*)d_in[8];
  const int*   cl   = (const int*)d_in[9];
  float* out = (float*)d_out;

  // ws layout (u16 elements): X1[8M] X2[8M] Wtq[1M] Wtk[1M] Wtv[1M] Q[8M] K[8M] V[8M]
  u16* ws  = (u16*)d_ws;
  const size_t M1 = 1024 * 1024;
  u16* X1  = ws;
  u16* X2  = ws + 8 * M1;
  u16* Wtq = ws + 16 * M1;
  u16* Wtk = Wtq + M1;
  u16* Wtv = Wtk + M1;
  u16* Qb  = Wtv + M1;
  u16* Kb  = Qb + 8 * M1;
  u16* Vb  = Kb + 8 * M1;
  u16* Vtb = X1;   // alias: X1 is dead after the projections dispatch completes

  conv_f32_bf16<<<2048, 256, 0, stream>>>(s1, X1, 2097152);
  conv_f32_bf16<<<2048, 256, 0, stream>>>(s2, X2, 2097152);
  dim3 wtb(32, 8);
  wtrans<<<dim3(32, 32), wtb, 0, stream>>>(Wq, Wtq);
  wtrans<<<dim3(32, 32), wtb, 0, stream>>>(Wk, Wtk);
  wtrans<<<dim3(32, 32), wtb, 0, stream>>>(Wv, Wtv);
  qkv_gemm3<<<dim3(8, 64, 3), 256, 0, stream>>>(X1, X2, Wtq, Wtk, Wtv, bq, bk, bv, Qb, Kb, Vb);
  vtrans<<<dim3(16, 128), dim3(64, 4), 0, stream>>>(Vb, Vtb);
  attn5<<<2048, 256, 0, stream>>>(Qb, Kb, Vtb, mask, cl, out);
}

// Round 5
// 259.403 us; speedup vs baseline: 1.4653x; 1.1302x over previous
//
#include <hip/hip_runtime.h>
#include <hip/hip_bf16.h>

typedef unsigned short u16;
typedef __attribute__((ext_vector_type(8))) short bf16x8;   // 8 bf16 = 4 VGPRs (MFMA A/B frag)
typedef __attribute__((ext_vector_type(4))) float f32x4;    // MFMA C/D frag
typedef __attribute__((ext_vector_type(4))) unsigned u32x4;

#define L2E 1.4426950408889634f

__device__ __forceinline__ u16 f2bf(float f) {
  unsigned u = __float_as_uint(f);
  u = u + 0x7fffu + ((u >> 16) & 1u);   // RNE
  return (u16)(u >> 16);
}
__device__ __forceinline__ float bf2f(short s) {
  return __uint_as_float(((unsigned)(u16)s) << 16);
}
__device__ __forceinline__ unsigned pkbf(float a, float b) {   // low = a, high = b (RNE)
  return ((unsigned)f2bf(b) << 16) | f2bf(a);
}
__device__ __forceinline__ float lo16(unsigned v) { return __uint_as_float(v << 16); }
__device__ __forceinline__ float hi16(unsigned v) { return __uint_as_float(v & 0xffff0000u); }

// ---------------- prep: f32 -> bf16 elementwise ----------------
__global__ void conv_f32_bf16(const float* __restrict__ in, u16* __restrict__ out, int n4) {
  int i = blockIdx.x * blockDim.x + threadIdx.x;
  int stride = gridDim.x * blockDim.x;
  for (; i < n4; i += stride) {
    float4 v = ((const float4*)in)[i];
    ushort4 o = make_ushort4(f2bf(v.x), f2bf(v.y), f2bf(v.z), f2bf(v.w));
    ((ushort4*)out)[i] = o;
  }
}

// ---------------- prep: W[k][n] f32 -> Wt[n][k] bf16 ----------------
__global__ void wtrans(const float* __restrict__ W, u16* __restrict__ Wt) {
  __shared__ float T[32][33];
  int k0 = blockIdx.y * 32, n0 = blockIdx.x * 32;
  int tx = threadIdx.x, ty = threadIdx.y;       // (32,8)
  #pragma unroll
  for (int j = 0; j < 4; ++j) T[ty + 8*j][tx] = W[(size_t)(k0 + ty + 8*j) * 1024 + n0 + tx];
  __syncthreads();
  #pragma unroll
  for (int j = 0; j < 4; ++j) Wt[(size_t)(n0 + ty + 8*j) * 1024 + k0 + tx] = f2bf(T[tx][ty + 8*j]);
}

// ---------------- QKV projection GEMM (3 fused via blockIdx.z), global_load_lds staging ----------------
__global__ __launch_bounds__(256) void qkv_gemm3(const u16* __restrict__ X1, const u16* __restrict__ X2,
                                                 const u16* __restrict__ Wtq, const u16* __restrict__ Wtk,
                                                 const u16* __restrict__ Wtv,
                                                 const float* __restrict__ bq, const float* __restrict__ bk,
                                                 const float* __restrict__ bv,
                                                 u16* __restrict__ Qo, u16* __restrict__ Ko, u16* __restrict__ Vo) {
  int z = blockIdx.z;
  const u16* X   = (z == 0) ? X1 : X2;
  const u16* Wt  = (z == 0) ? Wtq : (z == 1) ? Wtk : Wtv;
  const float* bias = (z == 0) ? bq : (z == 1) ? bk : bv;
  u16* outp = (z == 0) ? Qo : (z == 1) ? Ko : Vo;

  __shared__ __align__(16) u16 As[128 * 32];
  __shared__ __align__(16) u16 Bs[128 * 32];
  int tid = threadIdx.x;
  int m0 = blockIdx.y * 128, n0 = blockIdx.x * 128;
  int w = tid >> 6, l = tid & 63;
  int wm = w >> 1, wn = w & 1;
  const int4* Xs = (const int4*)X;
  const int4* Ws = (const int4*)Wt;
  int4* As4 = (int4*)As;
  int4* Bs4 = (int4*)Bs;
  f32x4 acc[4][4] = {};
  for (int kt = 0; kt < 32; ++kt) {
    #pragma unroll
    for (int c = 0; c < 2; ++c) {
      int i = c * 256 + tid;              // 0..511 int4 chunks; dest = wave-uniform base + lane*16
      int row = i >> 2, kc = i & 3;
      __builtin_amdgcn_global_load_lds(
          (const __attribute__((address_space(1))) void*)&Xs[(size_t)(m0 + row) * 128 + kt * 4 + kc],
          (__attribute__((address_space(3))) void*)&As4[i], 16, 0, 0);
      __builtin_amdgcn_global_load_lds(
          (const __attribute__((address_space(1))) void*)&Ws[(size_t)(n0 + row) * 128 + kt * 4 + kc],
          (__attribute__((address_space(3))) void*)&Bs4[i], 16, 0, 0);
    }
    __syncthreads();
    bf16x8 a[4], bb[4];
    #pragma unroll
    for (int mc = 0; mc < 4; ++mc) a[mc]  = *(const bf16x8*)&As[(wm*64 + mc*16 + (l & 15)) * 32 + (l >> 4) * 8];
    #pragma unroll
    for (int nc = 0; nc < 4; ++nc) bb[nc] = *(const bf16x8*)&Bs[(wn*64 + nc*16 + (l & 15)) * 32 + (l >> 4) * 8];
    #pragma unroll
    for (int mc = 0; mc < 4; ++mc)
      #pragma unroll
      for (int nc = 0; nc < 4; ++nc)
        acc[mc][nc] = __builtin_amdgcn_mfma_f32_16x16x32_bf16(a[mc], bb[nc], acc[mc][nc], 0, 0, 0);
    __syncthreads();
  }
  #pragma unroll
  for (int nc = 0; nc < 4; ++nc) {
    int n = n0 + wn * 64 + nc * 16 + (l & 15);
    float bvv = bias[n];
    int h = n >> 6, d = n & 63;
    #pragma unroll
    for (int mc = 0; mc < 4; ++mc) {
      int srow_base = m0 + wm * 64 + mc * 16 + (l >> 4) * 4;
      #pragma unroll
      for (int r = 0; r < 4; ++r) {
        int sm = srow_base + r;
        int b = sm >> 10, s = sm & 1023;
        outp[((size_t)((b * 16 + h) * 1024 + s)) * 64 + d] = f2bf(acc[mc][nc][r] + bvv);
      }
    }
  }
}

// ---------------- V [B,H,S,64] -> Vt [B,H,64,S] ----------------
__global__ void vtrans(const u16* __restrict__ V, u16* __restrict__ Vt) {
  __shared__ u16 T[64][65];
  int bh = blockIdx.y;
  int s0 = blockIdx.x * 64;
  int tx = threadIdx.x, ty = threadIdx.y;       // (64,4)
  #pragma unroll
  for (int j = 0; j < 16; ++j) T[ty + 4*j][tx] = V[((size_t)bh * 1024 + s0 + ty + 4*j) * 64 + tx];
  __syncthreads();
  #pragma unroll
  for (int j = 0; j < 16; ++j) Vt[((size_t)bh * 64 + ty + 4*j) * 1024 + s0 + tx] = T[tx][ty + 4*j];
}

// ---------------- fused double-softmax attention, v6 ----------------
// 4 waves = 2 qg x 2 kh. Wave (qg,kh): 16 q-rows (qg), kh-half (64 keys) of EVERY
// 128-key tile -> sp[64] u32/lane (no spill). K/V tiles staged once, shared by both
// kh waves. Softmax: in-lane + shfl + 2-way cross-kh LDS combine. kappa-permuted key
// order makes sp exactly the PV A-fragments. grid 4096 = 8 xcd x 16 bh x 32 qt.
// LDS 64KB -> 2 blocks/CU.
__global__ __launch_bounds__(256, 2) void attn6(const u16* __restrict__ Q, const u16* __restrict__ K,
                                                const u16* __restrict__ Vt, const float* __restrict__ mask,
                                                const int* __restrict__ clp, float* __restrict__ out) {
  __shared__ __align__(16) u16 Kl[2][128 * 64];   // 2 x 16KB : 128-key K tiles (dbuf)
  __shared__ __align__(16) u16 Vl[2][64 * 128];   // 2 x 16KB : 128-key V tiles (64 d-rows, dbuf)
  __shared__ float m1p[2][2][16];
  __shared__ float z1p[2][2][16];
  __shared__ float z2p[2][2][16];

  int bid = blockIdx.x;
  int xcd = bid & 7, idx = bid >> 3;
  int bh = xcd * 16 + (idx >> 5);   // 32 q-tile blocks share (b,h) within an XCD
  int qt = idx & 31;
  int b = bh >> 4, h = bh & 15;
  int tid = threadIdx.x;
  int w = tid >> 6, l = tid & 63;
  int lq = l & 15, g = l >> 4;
  int qg = w >> 1, kh = w & 1;
  int qb = qt * 32 + qg * 16;

  const float* mrow = mask + b * 1024;
  const u16* Kb = K + (size_t)bh * 65536;
  const u16* Vb = Vt + (size_t)bh * 65536;
  int cl = clp[0];

  // K stage: dest chunk i=(row,ch of 8); src chunk = ch ^ F(row), F = (row&3)|(((row>>3 ^ row>>4)&1)<<2)
#define STAGE_K(bi, t) do {                                                                  \
    _Pragma("unroll")                                                                        \
    for (int c_ = 0; c_ < 4; ++c_) {                                                         \
      int i_ = c_ * 256 + tid; int row_ = i_ >> 3, ch_ = i_ & 7;                             \
      int f_ = (row_ & 3) | ((((row_ >> 3) ^ (row_ >> 4)) & 1) << 2);                        \
      __builtin_amdgcn_global_load_lds(                                                      \
        (const __attribute__((address_space(1))) void*)(Kb + (size_t)((t) * 128 + row_) * 64 + ((ch_ ^ f_) * 8)), \
        (__attribute__((address_space(3))) void*)&Kl[bi][i_ * 8], 16, 0, 0);                 \
    } } while (0)

  // V stage (128-key tile): row=d (0..63, 16 chunks of 8 keys); src chunk = ch ^ (row&15)
#define STAGE_V(bi, t) do {                                                                  \
    _Pragma("unroll")                                                                        \
    for (int c_ = 0; c_ < 4; ++c_) {                                                         \
      int i_ = c_ * 256 + tid; int row_ = i_ >> 4, ch_ = i_ & 15;                            \
      __builtin_amdgcn_global_load_lds(                                                      \
        (const __attribute__((address_space(1))) void*)(Vb + (size_t)row_ * 1024 + (t) * 128 + ((ch_ ^ (row_ & 15)) * 8)), \
        (__attribute__((address_space(3))) void*)&Vl[bi][i_ * 8], 16, 0, 0);                 \
    } } while (0)

  STAGE_K(0, 0);

  const u16* Qp = Q + ((size_t)bh * 1024 + qb + lq) * 64 + g * 8;
  bf16x8 qf0 = *(const bf16x8*)Qp;
  bf16x8 qf1 = *(const bf16x8*)(Qp + 32);

  __syncthreads();   // K0 staged

  // ---- pass A: swapped QK^T over 8 K-tiles (wave's kh-half of each) ----
  const float sl2e = 0.125f * L2E;
  unsigned sp[64];
  float rmax = -1e30f;
  int cur = 0;
  #pragma unroll
  for (int t = 0; t < 8; ++t) {
    if (t < 7) STAGE_K(cur ^ 1, t + 1);
    else       STAGE_V(0, 0);
    #pragma unroll
    for (int ct = 0; ct < 4; ++ct) {
      int m = ct >> 1, c = ct & 1;
      int row128 = kh * 64 + m * 32 + ((lq >> 2) << 3) + c * 4 + (lq & 3);   // kappa
      int F = (row128 & 3) | ((((row128 >> 3) ^ (row128 >> 4)) & 1) << 2);
      bf16x8 kf0 = *(const bf16x8*)&Kl[cur][row128 * 64 + ((g ^ F) * 8)];
      bf16x8 kf1 = *(const bf16x8*)&Kl[cur][row128 * 64 + (((g + 4) ^ F) * 8)];
      f32x4 tt = {0.f, 0.f, 0.f, 0.f};
      tt = __builtin_amdgcn_mfma_f32_16x16x32_bf16(kf0, qf0, tt, 0, 0, 0);
      tt = __builtin_amdgcn_mfma_f32_16x16x32_bf16(kf1, qf1, tt, 0, 0, 0);
      // lane (g,lq): C slot sigma = ct*16 + g*4 + r -> key t*128 + kh*64 + m*32 + g*8 + c*4 + r
      float4 mk = *(const float4*)(mrow + t * 128 + kh * 64 + m * 32 + g * 8 + c * 4);
      float s0 = fmaf(tt[0], sl2e, mk.x * L2E);
      float s1 = fmaf(tt[1], sl2e, mk.y * L2E);
      float s2 = fmaf(tt[2], sl2e, mk.z * L2E);
      float s3 = fmaf(tt[3], sl2e, mk.w * L2E);
      rmax = fmaxf(rmax, fmaxf(fmaxf(s0, s1), fmaxf(s2, s3)));
      sp[t * 8 + m * 4 + c * 2 + 0] = pkbf(s0, s1);
      sp[t * 8 + m * 4 + c * 2 + 1] = pkbf(s2, s3);
    }
    __syncthreads();
    cur ^= 1;
  }

  // ---- softmax-1: cross-kh m1, E = exp2(s-m1), cross-kh Z1 ----
  rmax = fmaxf(rmax, __shfl_xor(rmax, 16));
  rmax = fmaxf(rmax, __shfl_xor(rmax, 32));
  if (l < 16) m1p[kh][qg][l] = rmax;
  __syncthreads();
  float m1 = fmaxf(m1p[0][qg][lq], m1p[1][qg][lq]);
  float z1 = 0.f;
  #pragma unroll
  for (int i = 0; i < 64; ++i) {
    unsigned v = sp[i];
    float e0 = __builtin_amdgcn_exp2f(lo16(v) - m1);
    float e1 = __builtin_amdgcn_exp2f(hi16(v) - m1);
    z1 += e0 + e1;
    sp[i] = pkbf(e0, e1);
  }
  z1 += __shfl_xor(z1, 16);
  z1 += __shfl_xor(z1, 32);
  if (l < 16) z1p[kh][qg][l] = z1;
  __syncthreads();
  float Z1 = z1p[0][qg][lq] + z1p[1][qg][lq];
  float iz1 = __builtin_amdgcn_rcpf(Z1);
  float cr = L2E * iz1;

  // ---- pass B: p2 = exp2(mask*L2E - cr*E), PV over 8 V-tiles (wave's kh-half) ----
  f32x4 acc[4] = {};
  float z2 = 0.f;
  #pragma unroll
  for (int t = 0; t < 8; ++t) {
    if (t < 7) STAGE_V((t + 1) & 1, t + 1);
    #pragma unroll
    for (int mm = 0; mm < 2; ++mm) {
      int kb = t * 128 + kh * 64 + mm * 32;     // global key base of this 32-chunk
      bf16x8 pf;
      if (cl) {
        float4 mk0 = *(const float4*)(mrow + kb + g * 8);
        float4 mk1 = *(const float4*)(mrow + kb + g * 8 + 4);
        unsigned e01 = sp[t * 8 + mm * 4 + 0], e23 = sp[t * 8 + mm * 4 + 1];
        unsigned e45 = sp[t * 8 + mm * 4 + 2], e67 = sp[t * 8 + mm * 4 + 3];
        float p0 = __builtin_amdgcn_exp2f(fmaf(mk0.x, L2E, -cr * lo16(e01)));
        float p1 = __builtin_amdgcn_exp2f(fmaf(mk0.y, L2E, -cr * hi16(e01)));
        float p2 = __builtin_amdgcn_exp2f(fmaf(mk0.z, L2E, -cr * lo16(e23)));
        float p3 = __builtin_amdgcn_exp2f(fmaf(mk0.w, L2E, -cr * hi16(e23)));
        float p4 = __builtin_amdgcn_exp2f(fmaf(mk1.x, L2E, -cr * lo16(e45)));
        float p5 = __builtin_amdgcn_exp2f(fmaf(mk1.y, L2E, -cr * hi16(e45)));
        float p6 = __builtin_amdgcn_exp2f(fmaf(mk1.z, L2E, -cr * lo16(e67)));
        float p7 = __builtin_amdgcn_exp2f(fmaf(mk1.w, L2E, -cr * hi16(e67)));
        z2 += ((p0 + p1) + (p2 + p3)) + ((p4 + p5) + (p6 + p7));
        u32x4 pk = {pkbf(p0, p1), pkbf(p2, p3), pkbf(p4, p5), pkbf(p6, p7)};
        pf = __builtin_bit_cast(bf16x8, pk);
      } else {
        u32x4 pk = {sp[t * 8 + mm * 4 + 0], sp[t * 8 + mm * 4 + 1],
                    sp[t * 8 + mm * 4 + 2], sp[t * 8 + mm * 4 + 3]};
        pf = __builtin_bit_cast(bf16x8, pk);
      }
      #pragma unroll
      for (int dc = 0; dc < 4; ++dc) {
        int row = dc * 16 + lq;
        int ch = (kh * 8 + mm * 4 + g) ^ (row & 15);
        bf16x8 vf = *(const bf16x8*)&Vl[t & 1][row * 128 + ch * 8];
        acc[dc] = __builtin_amdgcn_mfma_f32_16x16x32_bf16(pf, vf, acc[dc], 0, 0, 0);
      }
    }
    if (t < 7) __syncthreads();
  }

  // ---- epilogue: cross-kh reduce acc (overlay dead Kl) + scale ----
  z2 += __shfl_xor(z2, 16);
  z2 += __shfl_xor(z2, 32);
  if (l < 16) z2p[kh][qg][l] = z2;
  float* redF = (float*)&Kl[0][0];     // [2 qg][16 q][68 d-stride]
  if (kh == 1) {
    #pragma unroll
    for (int dc = 0; dc < 4; ++dc)
      #pragma unroll
      for (int r = 0; r < 4; ++r)
        redF[qg * 1088 + (g * 4 + r) * 68 + dc * 16 + lq] = acc[dc][r];
  }
  __syncthreads();
  if (kh == 0) {
    float Z2 = z2p[0][qg][lq] + z2p[1][qg][lq];
    float phi = cl ? __builtin_amdgcn_rcpf(Z2) : iz1;   // value for q-row lq
    #pragma unroll
    for (int r = 0; r < 4; ++r) {
      float ph = __shfl(phi, g * 4 + r);
      size_t orow = ((size_t)(b * 1024 + qb + g * 4 + r)) * 1024 + h * 64;
      #pragma unroll
      for (int dc = 0; dc < 4; ++dc) {
        float o = acc[dc][r] + redF[qg * 1088 + (g * 4 + r) * 68 + dc * 16 + lq];
        out[orow + dc * 16 + lq] = o * ph;
      }
    }
  }
#undef STAGE_K
#undef STAGE_V
}

extern "C" void kernel_launch(void* const* d_in, const int* in_sizes, int n_in,
                              void* d_out, int out_size, void* d_ws, size_t ws_size,
                              hipStream_t stream) {
  const float* s1   = (const float*)d_in[0];
  const float* s2   = (const float*)d_in[1];
  const float* mask = (const float*)d_in[2];
  const float* Wq   = (const float*)d_in[3];
  const float* bq   = (const float*)d_in[4];
  const float* Wk   = (const float*)d_in[5];
  const float* bk   = (const float*)d_in[6];
  const float* Wv   = (const float*)d_in[7];
  const float* bv   = (const float*)d_in[8];
  const int*   cl   = (const int*)d_in[9];
  float* out = (float*)d_out;

  // ws layout (u16 elements): X1[8M] X2[8M] Wtq[1M] Wtk[1M] Wtv[1M] Q[8M] K[8M] V[8M]
  u16* ws  = (u16*)d_ws;
  const size_t M1 = 1024 * 1024;
  u16* X1  = ws;
  u16* X2  = ws + 8 * M1;
  u16* Wtq = ws + 16 * M1;
  u16* Wtk = Wtq + M1;
  u16* Wtv = Wtk + M1;
  u16* Qb  = Wtv + M1;
  u16* Kb  = Qb + 8 * M1;
  u16* Vb  = Kb + 8 * M1;
  u16* Vtb = X1;   // alias: X1 is dead after the projections dispatch completes

  conv_f32_bf16<<<2048, 256, 0, stream>>>(s1, X1, 2097152);
  conv_f32_bf16<<<2048, 256, 0, stream>>>(s2, X2, 2097152);
  dim3 wtb(32, 8);
  wtrans<<<dim3(32, 32), wtb, 0, stream>>>(Wq, Wtq);
  wtrans<<<dim3(32, 32), wtb, 0, stream>>>(Wk, Wtk);
  wtrans<<<dim3(32, 32), wtb, 0, stream>>>(Wv, Wtv);
  qkv_gemm3<<<dim3(8, 64, 3), 256, 0, stream>>>(X1, X2, Wtq, Wtk, Wtv, bq, bk, bv, Qb, Kb, Vb);
  vtrans<<<dim3(16, 128), dim3(64, 4), 0, stream>>>(Vb, Vtb);
  attn6<<<4096, 256, 0, stream>>>(Qb, Kb, Vtb, mask, cl, out);
}